// Round 2
// baseline (517.393 us; speedup 1.0000x reference)
//
#include <hip/hip_runtime.h>
#include <cstdint>
#include <cstddef>

// ---------------- problem constants ----------------
#define B_  2
#define S_  4096
#define H_  2048
#define L_  2048
#define NH_ 16
#define M_  (B_*S_)     // 8192 rows
#define NC_ 64          // scan chunks
#define CS_ 64          // chunk size (NC_*CS_ == S_)

typedef unsigned short u16;
typedef short  bf8v  __attribute__((ext_vector_type(8)));   // 8 bf16 as raw shorts (MFMA operand)
typedef u16    u16x8 __attribute__((ext_vector_type(8)));
typedef float  f32x4 __attribute__((ext_vector_type(4)));

__device__ __forceinline__ float bf2f(u16 u){
  union { unsigned i; float f; } v; v.i = ((unsigned)u) << 16; return v.f;
}
__device__ __forceinline__ u16 f2bf(float f){
  union { float f; unsigned i; } v; v.f = f;
  unsigned u = v.i;
  return (u16)((u + 0x7FFFu + ((u >> 16) & 1u)) >> 16);   // RNE
}
__device__ __forceinline__ void gld16(const void* g, void* l){
  __builtin_amdgcn_global_load_lds((const __attribute__((address_space(1))) void*)g,
                                   (__attribute__((address_space(3))) void*)l, 16, 0, 0);
}

// ---------------- GEMM: C[M,N] = A[M,K](bf16) @ Bt[N,K](bf16)^T, + bias, opt gelu ----------
// BM=BN=128, BK=64, 256 threads (4 waves, 2x2), each wave 64x64 via 4x4 16x16x32 MFMA frags.
// LDS linear dest + XOR-swizzled global source + swizzled ds_read (bank-conflict-free).
// f32out=0 -> C is u16* (bf16); f32out=1 -> C is float*.
#define BM 128
#define BN 128
#define BKt 64

__global__ __launch_bounds__(256)
void gemm_bf16(const u16* __restrict__ A, int lda,
               const u16* __restrict__ Bt, int K,
               const float* __restrict__ bias,
               void* __restrict__ Cout, int ldc,
               int bd, int gelu_flag, int f32out)
{
  __shared__ u16 Alds[BM*BKt];
  __shared__ u16 Blds[BN*BKt];
  const int t    = threadIdx.x;
  const int lane = t & 63;
  const int w    = t >> 6;
  const int wr   = w >> 1, wc = w & 1;
  const int lr   = lane & 15, lk = lane >> 4;
  const int bx   = blockIdx.x, by = blockIdx.y;
  const long rowA0 = (long)by * BM;
  const long colB0 = (long)bx * BN;
  const long aoff  = bd ? (long)(bx >> 1) * 128 : 0;   // block-diag: head = bx/2, K=128
  const u16* Ag = A  + rowA0 * lda + aoff;
  const u16* Bg = Bt + colB0 * K;
  const int srow = t >> 3, scol = t & 7;

  f32x4 acc[4][4];
#pragma unroll
  for (int m=0;m<4;m++)
#pragma unroll
    for (int n=0;n<4;n++) acc[m][n] = (f32x4){0.f,0.f,0.f,0.f};

  const int nk = K / BKt;
  for (int kt = 0; kt < nk; ++kt) {
    if (kt) __syncthreads();
#pragma unroll
    for (int it = 0; it < 4; ++it) {
      int r  = it*32 + srow;                  // tile row 0..127
      int ca = (scol ^ (r & 7)) * 8;          // pre-swizzled source column (elems)
      gld16(Ag + (long)r*lda + (long)kt*BKt + ca, Alds + it*2048 + t*8);
      gld16(Bg + (long)r*K   + (long)kt*BKt + ca, Blds + it*2048 + t*8);
    }
    __syncthreads();
#pragma unroll
    for (int ks = 0; ks < 2; ++ks) {
      bf8v af[4], bfr[4];
#pragma unroll
      for (int m=0;m<4;m++){
        int r  = wr*64 + m*16 + lr;
        int kb = (ks*32 + lk*8)*2;
        af[m] = *(const bf8v*)((const char*)Alds + r*128 + (kb ^ ((r&7)<<4)));
      }
#pragma unroll
      for (int n=0;n<4;n++){
        int r  = wc*64 + n*16 + lr;
        int kb = (ks*32 + lk*8)*2;
        bfr[n] = *(const bf8v*)((const char*)Blds + r*128 + (kb ^ ((r&7)<<4)));
      }
#pragma unroll
      for (int m=0;m<4;m++)
#pragma unroll
        for (int n=0;n<4;n++)
          acc[m][n] = __builtin_amdgcn_mfma_f32_16x16x32_bf16(af[m], bfr[n], acc[m][n], 0, 0, 0);
    }
  }
  // epilogue: C/D layout col=lane&15, row=(lane>>4)*4+reg (m89-verified)
  u16*   Cb = (u16*)Cout;
  float* Cf = (float*)Cout;
#pragma unroll
  for (int m=0;m<4;m++){
    long row = rowA0 + wr*64 + m*16 + lk*4;
#pragma unroll
    for (int n=0;n<4;n++){
      int col = (int)colB0 + wc*64 + n*16 + lr;
      float bv = bias[col];
#pragma unroll
      for (int rr=0; rr<4; ++rr){
        float v = acc[m][n][rr] + bv;
        if (gelu_flag) {
          // jax.nn.gelu default (tanh approx)
          float u  = 0.7978845608028654f * (v + 0.044715f * v*v*v);
          float tu = fminf(fmaxf(2.f*u, -80.f), 80.f);
          float e  = __expf(tu);
          float th = (e - 1.f) / (e + 1.f);
          v = 0.5f * v * (1.f + th);
        }
        if (f32out) Cf[(row+rr)*(long)ldc + col] = v;
        else        Cb[(row+rr)*(long)ldc + col] = f2bf(v);
      }
    }
  }
}

// ---------------- tiled transpose + fp32->bf16 convert: out[c][r] = in[r][c] ----------------
__global__ __launch_bounds__(256)
void transpose_cvt(const float* __restrict__ in, u16* __restrict__ out, int R, int C)
{
  __shared__ float tile[64][65];
  int t  = threadIdx.x;
  int tc = blockIdx.x * 64, tr = blockIdx.y * 64;
  int r  = t >> 2, c0 = (t & 3) * 16;
#pragma unroll
  for (int i=0;i<4;i++)
    *(f32x4*)(&tile[r][c0 + i*4]) = *(const f32x4*)(in + (long)(tr+r)*C + tc + c0 + i*4);
  __syncthreads();
  int nl = t >> 2;
#pragma unroll
  for (int it=0; it<2; ++it){
    int g = (t & 3) + it*4;
    u16x8 o;
#pragma unroll
    for (int e=0;e<8;e++) o[e] = f2bf(tile[g*8+e][nl]);
    *(u16x8*)(out + (long)(tc+nl)*R + tr + g*8) = o;
  }
}

// ---------------- small prep: gate weights pack+transpose, gate bias pack, c8 --------------
__global__ __launch_bounds__(256)
void prep_small(const float* __restrict__ igw, const float* __restrict__ rgw,
                const float* __restrict__ igb, const float* __restrict__ rgb,
                const float* __restrict__ rec, u16* __restrict__ Gt,
                float* __restrict__ gbias, float* __restrict__ c8)
{
  int idx = blockIdx.x*256 + threadIdx.x;       // NH_*256*128 = 524288
  int d = idx & 127, g = idx >> 7;
  int n = g >> 8, j = g & 255;
  float v = (j < 128) ? igw[(n*128 + d)*128 + j] : rgw[(n*128 + d)*128 + (j-128)];
  Gt[idx] = f2bf(v);
  if (idx < NH_*256) {
    int nn = idx >> 8, jj = idx & 255;
    gbias[idx] = (jj < 128) ? igb[nn*128 + jj] : rgb[nn*128 + jj - 128];
  }
  if (idx < L_) c8[idx] = -8.f * log1pf(__expf(rec[idx]));
}

// ---------------- X fp32 -> bf16 ----------------
__global__ __launch_bounds__(256)
void cvt_x(const float* __restrict__ X, u16* __restrict__ Xb)
{
  long idx = (long)blockIdx.x*256 + threadIdx.x;   // per 8 elems
  f32x4 a = *(const f32x4*)(X + idx*8);
  f32x4 b = *(const f32x4*)(X + idx*8 + 4);
  u16x8 o;
#pragma unroll
  for (int e=0;e<4;e++){ o[e] = f2bf(a[e]); o[4+e] = f2bf(b[e]); }
  *(u16x8*)(Xb + idx*8) = o;
}

// ---------------- causal depthwise conv1d (K=4) + conv bias ----------------
__global__ __launch_bounds__(256)
void conv_k(const u16* __restrict__ X, const float* __restrict__ cw,
            const float* __restrict__ cb, u16* __restrict__ O)
{
  long idx = (long)blockIdx.x*256 + threadIdx.x;   // per 8 channels
  int l8 = (int)(idx & (L_/8 - 1));
  long bs = idx >> 8;                              // L_/8 == 256
  int s = (int)(bs & (S_-1));
  int b = (int)(bs >> 12);
  int l0 = l8*8;
  float acc[8];
#pragma unroll
  for (int j=0;j<8;j++) acc[j] = cb[l0+j];
#pragma unroll
  for (int k=0;k<4;k++){
    int sp = s - 3 + k;
    if (sp >= 0) {
      bf8v xv = *(const bf8v*)(X + ((long)b*S_ + sp)*L_ + l0);
#pragma unroll
      for (int j=0;j<8;j++){
        f32x4 wj = *(const f32x4*)(cw + (long)(l0+j)*4);
        acc[j] += bf2f((u16)xv[j]) * wj[k];
      }
    }
  }
  u16x8 o;
#pragma unroll
  for (int j=0;j<8;j++) o[j] = f2bf(acc[j]);
  *(u16x8*)(O + idx*8) = o;
}

// ---------------- gates pointwise: sigmoid, a, mult, reset handling ----------------
__global__ __launch_bounds__(256)
void gates_pw(const u16* __restrict__ Gp, const u16* __restrict__ xc,
              const float* __restrict__ c8, const int* __restrict__ pos,
              u16* __restrict__ Ae, u16* __restrict__ Nr)
{
  long idx = (long)blockIdx.x*256 + threadIdx.x;   // per 8 channels
  int l8 = (int)(idx & 255);
  long bs = idx >> 8;
  int l0 = l8*8;
  int n  = l0 >> 7;
  int e  = l0 & 127;
  const u16* gp = Gp + bs*(NH_*256) + n*256 + e;
  bf8v igv = *(const bf8v*)gp;
  bf8v rgv = *(const bf8v*)(gp + 128);
  bf8v xv  = *(const bf8v*)(xc + idx*8);
  bool reset = (pos[bs] == 0);
  f32x4 c8a = *(const f32x4*)(c8 + l0);
  f32x4 c8b = *(const f32x4*)(c8 + l0 + 4);
  u16x8 ae, nr;
#pragma unroll
  for (int j=0;j<8;j++){
    float ig = 1.f / (1.f + __expf(-bf2f((u16)igv[j])));
    float rg = 1.f / (1.f + __expf(-bf2f((u16)rgv[j])));
    float cc = (j < 4) ? c8a[j] : c8b[j-4];
    float la = cc * rg;
    float a  = __expf(la);
    float mult = reset ? 1.f : sqrtf(fmaxf(1.f - __expf(2.f*la), 0.f));
    float x = bf2f((u16)xv[j]);
    nr[j] = f2bf(x * ig * mult);
    ae[j] = f2bf(reset ? 0.f : a);
  }
  *(u16x8*)(Ae + idx*8) = ae;
  *(u16x8*)(Nr + idx*8) = nr;
}

// ---------------- chunked scan ----------------
__global__ __launch_bounds__(256)
void scan1(const u16* __restrict__ Ae, const u16* __restrict__ Nr,
           float* __restrict__ Ach, float* __restrict__ Hch)
{
  int t = threadIdx.x;
  int l = (blockIdx.x & 7)*256 + t;
  int c = (blockIdx.x >> 3) & (NC_-1);
  int b = blockIdx.x >> 9;
  long base = ((long)b*S_ + (long)c*CS_)*L_ + l;
  float A = 1.f, h = 0.f;
#pragma unroll 8
  for (int s=0; s<CS_; ++s){
    float a = bf2f(Ae[base + (long)s*L_]);
    float x = bf2f(Nr[base + (long)s*L_]);
    h = fmaf(a, h, x);
    A *= a;
  }
  long o = ((long)b*NC_ + c)*L_ + l;
  Ach[o] = A; Hch[o] = h;
}

__global__ __launch_bounds__(256)
void scan2(const float* __restrict__ Ach, const float* __restrict__ Hch,
           float* __restrict__ Hcar)
{
  int idx = blockIdx.x*256 + threadIdx.x;   // B_*L_ = 4096
  int b = idx >> 11, l = idx & (L_-1);
  float h = 0.f;
  for (int c=0; c<NC_; ++c){
    long o = ((long)b*NC_ + c)*L_ + l;
    Hcar[o] = h;
    h = fmaf(Ach[o], h, Hch[o]);
  }
}

__global__ __launch_bounds__(256)
void scan3(const u16* __restrict__ Ae, const u16* __restrict__ Nr,
           const float* __restrict__ Hcar, const u16* __restrict__ Y,
           u16* __restrict__ Z)
{
  int t = threadIdx.x;
  int l = (blockIdx.x & 7)*256 + t;
  int c = (blockIdx.x >> 3) & (NC_-1);
  int b = blockIdx.x >> 9;
  long base = ((long)b*S_ + (long)c*CS_)*L_ + l;
  float h = Hcar[((long)b*NC_ + c)*L_ + l];
#pragma unroll 8
  for (int s=0; s<CS_; ++s){
    long o = base + (long)s*L_;
    h = fmaf(bf2f(Ae[o]), h, bf2f(Nr[o]));
    Z[o] = f2bf(h * bf2f(Y[o]));
  }
}

// ---------------- launch ----------------
extern "C" void kernel_launch(void* const* d_in, const int* in_sizes, int n_in,
                              void* d_out, int out_size, void* d_ws, size_t ws_size,
                              hipStream_t stream)
{
  (void)in_sizes; (void)n_in; (void)out_size; (void)ws_size;
  const float* X    = (const float*)d_in[0];
  const float* Wy   = (const float*)d_in[1];
  const float* by   = (const float*)d_in[2];
  const float* Wx   = (const float*)d_in[3];
  const float* bx   = (const float*)d_in[4];
  const float* cw   = (const float*)d_in[5];
  const float* cb   = (const float*)d_in[6];
  const float* rec  = (const float*)d_in[7];
  const float* igw  = (const float*)d_in[8];
  const float* igb  = (const float*)d_in[9];
  const float* rgw  = (const float*)d_in[10];
  const float* rgb  = (const float*)d_in[11];
  const float* Wout = (const float*)d_in[12];
  const float* bout = (const float*)d_in[13];
  const int*   pos  = (const int*)d_in[14];
  float* out = (float*)d_out;   // reference output dtype is float32

  char* ws = (char*)d_ws;
  // workspace layout (~229 MB; all offsets naturally 256B-aligned)
  size_t o_Xbf  = 0;                                  // 33.5MB  } Gp region (67MB)
  size_t o_Xlin = o_Xbf  + (size_t)M_*H_*2;           // 33.5MB  }
  size_t o_WyT  = o_Xlin + (size_t)M_*L_*2;
  size_t o_WxT  = o_WyT  + (size_t)H_*L_*2;
  size_t o_WoT  = o_WxT  + (size_t)H_*L_*2;
  size_t o_Gt   = o_WoT  + (size_t)L_*H_*2;
  size_t o_gb   = o_Gt   + (size_t)NH_*256*128*2;
  size_t o_c8   = o_gb   + 4096*4;
  size_t o_Y    = o_c8   + 2048*4;
  size_t o_xc   = o_Y    + (size_t)M_*L_*2;           // xconv, later reused as Z
  size_t o_Ae   = o_xc   + (size_t)M_*L_*2;
  size_t o_Nr   = o_Ae   + (size_t)M_*L_*2;
  size_t o_Ach  = o_Nr   + (size_t)M_*L_*2;
  size_t o_Hch  = o_Ach  + (size_t)B_*NC_*L_*4;
  size_t o_Hca  = o_Hch  + (size_t)B_*NC_*L_*4;

  u16*   Xbf   = (u16*)(ws + o_Xbf);
  u16*   Xlin  = (u16*)(ws + o_Xlin);
  u16*   WyT   = (u16*)(ws + o_WyT);
  u16*   WxT   = (u16*)(ws + o_WxT);
  u16*   WoT   = (u16*)(ws + o_WoT);
  u16*   Gt    = (u16*)(ws + o_Gt);
  float* gbias = (float*)(ws + o_gb);
  float* c8    = (float*)(ws + o_c8);
  u16*   Y     = (u16*)(ws + o_Y);
  u16*   xconv = (u16*)(ws + o_xc);
  u16*   Gp    = (u16*)(ws + o_Xbf);   // reuse: Xbf+Xlin dead after the two big GEMMs
  u16*   Z     = (u16*)(ws + o_xc);    // reuse: xconv dead after gates_pw
  u16*   Ae    = (u16*)(ws + o_Ae);
  u16*   Nr    = (u16*)(ws + o_Nr);
  float* Ach   = (float*)(ws + o_Ach);
  float* Hch   = (float*)(ws + o_Hch);
  float* Hcar  = (float*)(ws + o_Hca);

  dim3 blk(256);
  // prep
  transpose_cvt<<<dim3(32,32), blk, 0, stream>>>(Wy,  WyT, 2048, 2048);
  transpose_cvt<<<dim3(32,32), blk, 0, stream>>>(Wx,  WxT, 2048, 2048);
  transpose_cvt<<<dim3(32,32), blk, 0, stream>>>(Wout,WoT, 2048, 2048);
  prep_small<<<dim3(2048), blk, 0, stream>>>(igw, rgw, igb, rgb, rec, Gt, gbias, c8);
  cvt_x<<<dim3(8192), blk, 0, stream>>>(X, Xbf);
  // y branch + x branch linears
  gemm_bf16<<<dim3(16,64), blk, 0, stream>>>(Xbf, H_, WyT, H_, by, Y,    L_, 0, 1, 0);
  gemm_bf16<<<dim3(16,64), blk, 0, stream>>>(Xbf, H_, WxT, H_, bx, Xlin, L_, 0, 0, 0);
  // conv
  conv_k<<<dim3(8192), blk, 0, stream>>>(Xlin, cw, cb, xconv);
  // block-diagonal gate GEMM (writes Gp over dead Xbf/Xlin region)
  gemm_bf16<<<dim3(32,64), blk, 0, stream>>>(xconv, L_, Gt, 128, gbias, Gp, NH_*256, 1, 0, 0);
  // pointwise gates
  gates_pw<<<dim3(8192), blk, 0, stream>>>(Gp, xconv, c8, pos, Ae, Nr);
  // chunked scan
  scan1<<<dim3(1024), blk, 0, stream>>>(Ae, Nr, Ach, Hch);
  scan2<<<dim3(16),   blk, 0, stream>>>(Ach, Hch, Hcar);
  scan3<<<dim3(1024), blk, 0, stream>>>(Ae, Nr, Hcar, Y, Z);
  // output projection into d_out (fp32)
  gemm_bf16<<<dim3(16,64), blk, 0, stream>>>(Z, L_, WoT, L_, bout, out, H_, 0, 0, 1);
}

// Round 3
// 498.372 us; speedup vs baseline: 1.0382x; 1.0382x over previous
//
#include <hip/hip_runtime.h>
#include <cstdint>
#include <cstddef>

// ---------------- problem constants ----------------
#define B_  2
#define S_  4096
#define H_  2048
#define L_  2048
#define NH_ 16
#define M_  (B_*S_)     // 8192 rows
#define NC_ 64          // scan chunks
#define CS_ 64          // chunk size (NC_*CS_ == S_)

typedef unsigned short u16;
typedef short  bf8v  __attribute__((ext_vector_type(8)));   // 8 bf16 as raw shorts (MFMA operand)
typedef u16    u16x8 __attribute__((ext_vector_type(8)));
typedef float  f32x4 __attribute__((ext_vector_type(4)));

__device__ __forceinline__ float bf2f(u16 u){
  union { unsigned i; float f; } v; v.i = ((unsigned)u) << 16; return v.f;
}
__device__ __forceinline__ u16 f2bf(float f){
  union { float f; unsigned i; } v; v.f = f;
  unsigned u = v.i;
  return (u16)((u + 0x7FFFu + ((u >> 16) & 1u)) >> 16);   // RNE
}
__device__ __forceinline__ void gld16(const void* g, void* l){
  __builtin_amdgcn_global_load_lds((const __attribute__((address_space(1))) void*)g,
                                   (__attribute__((address_space(3))) void*)l, 16, 0, 0);
}

// ---------------- GEMM: C[M,N] = A[M,K](bf16) @ Bt[N,K](bf16)^T, + bias, opt gelu ----------
// BM=BN=128, BK=64, 256 threads (4 waves, 2x2), each wave 64x64 via 4x4 16x16x32 MFMA frags.
// Latency-hiding order per K-step: ds_read all frags -> barrier -> issue next-tile
// global_load_lds -> MFMA (prefetch lands under MFMA) -> syncthreads (vmcnt(0) drain).
// XCD M-band swizzle: hw-XCD k gets a contiguous by-band -> per-K-step A/B slices L2-resident.
// Fused mode (C2 != null): cols [0,L_) -> C1 (gelu per flag), cols [L_,2L_) -> C2 (no gelu).
#define BM 128
#define BN 128
#define BKt 64

__global__ __launch_bounds__(256)
void gemm_bf16(const u16* __restrict__ A, int lda,
               const u16* __restrict__ Bt, int K,
               const float* __restrict__ bias1, const float* __restrict__ bias2,
               void* __restrict__ C1, u16* __restrict__ C2, int ldc,
               int bd, int gelu_flag, int f32out)
{
  __shared__ u16 Alds[BM*BKt];
  __shared__ u16 Blds[BN*BKt];
  const int t    = threadIdx.x;
  const int lane = t & 63;
  const int w    = t >> 6;
  const int wr   = w >> 1, wc = w & 1;
  const int lr   = lane & 15, lk = lane >> 4;

  // XCD-aware bijective swizzle: hw id -> logical tile so XCD k owns a contiguous M-band
  const int nwg = gridDim.x * gridDim.y;
  const int bid = blockIdx.y * gridDim.x + blockIdx.x;
  const int cpx = nwg >> 3;                       // all grids here are multiples of 8
  const int swz = (bid & 7) * cpx + (bid >> 3);
  const int bx  = swz % gridDim.x;
  const int by  = swz / gridDim.x;

  const long rowA0 = (long)by * BM;
  const long colB0 = (long)bx * BN;
  const long aoff  = bd ? (long)(bx >> 1) * 128 : 0;   // block-diag: head = bx/2, K=128
  const u16* Ag = A  + rowA0 * lda + aoff;
  const u16* Bg = Bt + colB0 * K;
  const int srow = t >> 3, scol = t & 7;

#define STAGE(KT) do {                                                     \
    _Pragma("unroll")                                                      \
    for (int it = 0; it < 4; ++it) {                                       \
      int r  = it*32 + srow;                                               \
      int ca = (scol ^ (r & 7)) * 8;                                       \
      gld16(Ag + (long)r*lda + (long)(KT)*BKt + ca, Alds + it*2048 + t*8); \
      gld16(Bg + (long)r*K   + (long)(KT)*BKt + ca, Blds + it*2048 + t*8); \
    } } while(0)

  f32x4 acc[4][4];
#pragma unroll
  for (int m=0;m<4;m++)
#pragma unroll
    for (int n=0;n<4;n++) acc[m][n] = (f32x4){0.f,0.f,0.f,0.f};

  const int nk = K / BKt;
  STAGE(0);
  __syncthreads();                                 // tile 0 landed (vmcnt(0) + barrier)

  for (int kt = 0; kt < nk; ++kt) {
    // 1) LDS -> registers: all 16 frags of current tile
    bf8v af[4][2], bv[4][2];
#pragma unroll
    for (int m=0;m<4;m++)
#pragma unroll
      for (int ks=0;ks<2;ks++){
        int r  = wr*64 + m*16 + lr;
        int kb = (ks*32 + lk*8)*2;
        af[m][ks] = *(const bf8v*)((const char*)Alds + r*128 + (kb ^ ((r&7)<<4)));
      }
#pragma unroll
    for (int n=0;n<4;n++)
#pragma unroll
      for (int ks=0;ks<2;ks++){
        int r  = wc*64 + n*16 + lr;
        int kb = (ks*32 + lk*8)*2;
        bv[n][ks] = *(const bf8v*)((const char*)Blds + r*128 + (kb ^ ((r&7)<<4)));
      }
    __syncthreads();                               // lgkmcnt(0): LDS fully in regs, all waves

    // 2) issue next tile's loads now -> land during MFMA
    if (kt + 1 < nk) STAGE(kt + 1);
    __builtin_amdgcn_sched_barrier(0);             // keep gld issue ahead of MFMA

    // 3) MFMA on registers
#pragma unroll
    for (int ks=0;ks<2;ks++)
#pragma unroll
      for (int m=0;m<4;m++)
#pragma unroll
        for (int n=0;n<4;n++)
          acc[m][n] = __builtin_amdgcn_mfma_f32_16x16x32_bf16(af[m][ks], bv[n][ks], acc[m][n], 0, 0, 0);

    // 4) drain prefetch (implicit vmcnt(0)) + barrier
    if (kt + 1 < nk) __syncthreads();
  }
#undef STAGE

  // epilogue: C/D layout col=lane&15, row=(lane>>4)*4+reg (m89-verified)
  u16*   Cb = (u16*)C1;
  float* Cf = (float*)C1;
#pragma unroll
  for (int m=0;m<4;m++){
    long row = rowA0 + wr*64 + m*16 + lk*4;
#pragma unroll
    for (int n=0;n<4;n++){
      int col = (int)colB0 + wc*64 + n*16 + lr;
      bool sec = (C2 != nullptr) && (col >= L_);
      float bvv = sec ? bias2[col - L_] : bias1[col];
      bool gel = gelu_flag && !sec;
#pragma unroll
      for (int rr=0; rr<4; ++rr){
        float v = acc[m][n][rr] + bvv;
        if (gel) {
          // jax.nn.gelu default (tanh approx)
          float u  = 0.7978845608028654f * (v + 0.044715f * v*v*v);
          float tu = fminf(fmaxf(2.f*u, -80.f), 80.f);
          float e  = __expf(tu);
          float th = (e - 1.f) / (e + 1.f);
          v = 0.5f * v * (1.f + th);
        }
        if (sec)          C2[(row+rr)*(long)L_ + (col - L_)] = f2bf(v);
        else if (f32out)  Cf[(row+rr)*(long)ldc + col] = v;
        else              Cb[(row+rr)*(long)ldc + col] = f2bf(v);
      }
    }
  }
}

// ---------------- tiled transpose + fp32->bf16 convert: out[c][r] = in[r][c] ----------------
__global__ __launch_bounds__(256)
void transpose_cvt(const float* __restrict__ in, u16* __restrict__ out, int R, int C)
{
  __shared__ float tile[64][65];
  int t  = threadIdx.x;
  int tc = blockIdx.x * 64, tr = blockIdx.y * 64;
  int r  = t >> 2, c0 = (t & 3) * 16;
#pragma unroll
  for (int i=0;i<4;i++)
    *(f32x4*)(&tile[r][c0 + i*4]) = *(const f32x4*)(in + (long)(tr+r)*C + tc + c0 + i*4);
  __syncthreads();
  int nl = t >> 2;
#pragma unroll
  for (int it=0; it<2; ++it){
    int g = (t & 3) + it*4;
    u16x8 o;
#pragma unroll
    for (int e=0;e<8;e++) o[e] = f2bf(tile[g*8+e][nl]);
    *(u16x8*)(out + (long)(tc+nl)*R + tr + g*8) = o;
  }
}

// ---------------- small prep: gate weights pack+transpose, gate bias pack, c8 --------------
__global__ __launch_bounds__(256)
void prep_small(const float* __restrict__ igw, const float* __restrict__ rgw,
                const float* __restrict__ igb, const float* __restrict__ rgb,
                const float* __restrict__ rec, u16* __restrict__ Gt,
                float* __restrict__ gbias, float* __restrict__ c8)
{
  int idx = blockIdx.x*256 + threadIdx.x;       // NH_*256*128 = 524288
  int d = idx & 127, g = idx >> 7;
  int n = g >> 8, j = g & 255;
  float v = (j < 128) ? igw[(n*128 + d)*128 + j] : rgw[(n*128 + d)*128 + (j-128)];
  Gt[idx] = f2bf(v);
  if (idx < NH_*256) {
    int nn = idx >> 8, jj = idx & 255;
    gbias[idx] = (jj < 128) ? igb[nn*128 + jj] : rgb[nn*128 + jj - 128];
  }
  if (idx < L_) c8[idx] = -8.f * log1pf(__expf(rec[idx]));
}

// ---------------- X fp32 -> bf16 ----------------
__global__ __launch_bounds__(256)
void cvt_x(const float* __restrict__ X, u16* __restrict__ Xb)
{
  long idx = (long)blockIdx.x*256 + threadIdx.x;   // per 8 elems
  f32x4 a = *(const f32x4*)(X + idx*8);
  f32x4 b = *(const f32x4*)(X + idx*8 + 4);
  u16x8 o;
#pragma unroll
  for (int e=0;e<4;e++){ o[e] = f2bf(a[e]); o[4+e] = f2bf(b[e]); }
  *(u16x8*)(Xb + idx*8) = o;
}

// ---------------- causal depthwise conv1d (K=4) + conv bias ----------------
__global__ __launch_bounds__(256)
void conv_k(const u16* __restrict__ X, const float* __restrict__ cw,
            const float* __restrict__ cb, u16* __restrict__ O)
{
  long idx = (long)blockIdx.x*256 + threadIdx.x;   // per 8 channels
  int l8 = (int)(idx & (L_/8 - 1));
  long bs = idx >> 8;                              // L_/8 == 256
  int s = (int)(bs & (S_-1));
  int b = (int)(bs >> 12);
  int l0 = l8*8;
  float acc[8];
#pragma unroll
  for (int j=0;j<8;j++) acc[j] = cb[l0+j];
#pragma unroll
  for (int k=0;k<4;k++){
    int sp = s - 3 + k;
    if (sp >= 0) {
      bf8v xv = *(const bf8v*)(X + ((long)b*S_ + sp)*L_ + l0);
#pragma unroll
      for (int j=0;j<8;j++){
        f32x4 wj = *(const f32x4*)(cw + (long)(l0+j)*4);
        acc[j] += bf2f((u16)xv[j]) * wj[k];
      }
    }
  }
  u16x8 o;
#pragma unroll
  for (int j=0;j<8;j++) o[j] = f2bf(acc[j]);
  *(u16x8*)(O + idx*8) = o;
}

// ---------------- gates pointwise: sigmoid, a, mult, reset handling ----------------
__global__ __launch_bounds__(256)
void gates_pw(const u16* __restrict__ Gp, const u16* __restrict__ xc,
              const float* __restrict__ c8, const int* __restrict__ pos,
              u16* __restrict__ Ae, u16* __restrict__ Nr)
{
  long idx = (long)blockIdx.x*256 + threadIdx.x;   // per 8 channels
  int l8 = (int)(idx & 255);
  long bs = idx >> 8;
  int l0 = l8*8;
  int n  = l0 >> 7;
  int e  = l0 & 127;
  const u16* gp = Gp + bs*(NH_*256) + n*256 + e;
  bf8v igv = *(const bf8v*)gp;
  bf8v rgv = *(const bf8v*)(gp + 128);
  bf8v xv  = *(const bf8v*)(xc + idx*8);
  bool reset = (pos[bs] == 0);
  f32x4 c8a = *(const f32x4*)(c8 + l0);
  f32x4 c8b = *(const f32x4*)(c8 + l0 + 4);
  u16x8 ae, nr;
#pragma unroll
  for (int j=0;j<8;j++){
    float ig = 1.f / (1.f + __expf(-bf2f((u16)igv[j])));
    float rg = 1.f / (1.f + __expf(-bf2f((u16)rgv[j])));
    float cc = (j < 4) ? c8a[j] : c8b[j-4];
    float la = cc * rg;
    float a  = __expf(la);
    float mult = reset ? 1.f : sqrtf(fmaxf(1.f - __expf(2.f*la), 0.f));
    float x = bf2f((u16)xv[j]);
    nr[j] = f2bf(x * ig * mult);
    ae[j] = f2bf(reset ? 0.f : a);
  }
  *(u16x8*)(Ae + idx*8) = ae;
  *(u16x8*)(Nr + idx*8) = nr;
}

// ---------------- chunked scan ----------------
__global__ __launch_bounds__(256)
void scan1(const u16* __restrict__ Ae, const u16* __restrict__ Nr,
           float* __restrict__ Ach, float* __restrict__ Hch)
{
  int t = threadIdx.x;
  int l = (blockIdx.x & 7)*256 + t;
  int c = (blockIdx.x >> 3) & (NC_-1);
  int b = blockIdx.x >> 9;
  long base = ((long)b*S_ + (long)c*CS_)*L_ + l;
  float A = 1.f, h = 0.f;
#pragma unroll 8
  for (int s=0; s<CS_; ++s){
    float a = bf2f(Ae[base + (long)s*L_]);
    float x = bf2f(Nr[base + (long)s*L_]);
    h = fmaf(a, h, x);
    A *= a;
  }
  long o = ((long)b*NC_ + c)*L_ + l;
  Ach[o] = A; Hch[o] = h;
}

__global__ __launch_bounds__(256)
void scan2(const float* __restrict__ Ach, const float* __restrict__ Hch,
           float* __restrict__ Hcar)
{
  int idx = blockIdx.x*256 + threadIdx.x;   // B_*L_ = 4096
  int b = idx >> 11, l = idx & (L_-1);
  float h = 0.f;
  for (int c=0; c<NC_; ++c){
    long o = ((long)b*NC_ + c)*L_ + l;
    Hcar[o] = h;
    h = fmaf(Ach[o], h, Hch[o]);
  }
}

__global__ __launch_bounds__(256)
void scan3(const u16* __restrict__ Ae, const u16* __restrict__ Nr,
           const float* __restrict__ Hcar, const u16* __restrict__ Y,
           u16* __restrict__ Z)
{
  int t = threadIdx.x;
  int l = (blockIdx.x & 7)*256 + t;
  int c = (blockIdx.x >> 3) & (NC_-1);
  int b = blockIdx.x >> 9;
  long base = ((long)b*S_ + (long)c*CS_)*L_ + l;
  float h = Hcar[((long)b*NC_ + c)*L_ + l];
#pragma unroll 8
  for (int s=0; s<CS_; ++s){
    long o = base + (long)s*L_;
    h = fmaf(bf2f(Ae[o]), h, bf2f(Nr[o]));
    Z[o] = f2bf(h * bf2f(Y[o]));
  }
}

// ---------------- launch ----------------
extern "C" void kernel_launch(void* const* d_in, const int* in_sizes, int n_in,
                              void* d_out, int out_size, void* d_ws, size_t ws_size,
                              hipStream_t stream)
{
  (void)in_sizes; (void)n_in; (void)out_size; (void)ws_size;
  const float* X    = (const float*)d_in[0];
  const float* Wy   = (const float*)d_in[1];
  const float* by   = (const float*)d_in[2];
  const float* Wx   = (const float*)d_in[3];
  const float* bx   = (const float*)d_in[4];
  const float* cw   = (const float*)d_in[5];
  const float* cb   = (const float*)d_in[6];
  const float* rec  = (const float*)d_in[7];
  const float* igw  = (const float*)d_in[8];
  const float* igb  = (const float*)d_in[9];
  const float* rgw  = (const float*)d_in[10];
  const float* rgb  = (const float*)d_in[11];
  const float* Wout = (const float*)d_in[12];
  const float* bout = (const float*)d_in[13];
  const int*   pos  = (const int*)d_in[14];
  float* out = (float*)d_out;   // reference output dtype is float32

  char* ws = (char*)d_ws;
  // workspace layout (~229 MB; all offsets naturally 256B-aligned)
  size_t o_Xbf  = 0;                                  // 33.5MB  } Gp region (67MB)
  size_t o_Xlin = o_Xbf  + (size_t)M_*H_*2;           // 33.5MB  }
  size_t o_WyT  = o_Xlin + (size_t)M_*L_*2;           // WyT then WxT contiguous => fused Bt
  size_t o_WxT  = o_WyT  + (size_t)H_*L_*2;
  size_t o_WoT  = o_WxT  + (size_t)H_*L_*2;
  size_t o_Gt   = o_WoT  + (size_t)L_*H_*2;
  size_t o_gb   = o_Gt   + (size_t)NH_*256*128*2;
  size_t o_c8   = o_gb   + 4096*4;
  size_t o_Y    = o_c8   + 2048*4;
  size_t o_xc   = o_Y    + (size_t)M_*L_*2;           // xconv, later reused as Z
  size_t o_Ae   = o_xc   + (size_t)M_*L_*2;
  size_t o_Nr   = o_Ae   + (size_t)M_*L_*2;
  size_t o_Ach  = o_Nr   + (size_t)M_*L_*2;
  size_t o_Hch  = o_Ach  + (size_t)B_*NC_*L_*4;
  size_t o_Hca  = o_Hch  + (size_t)B_*NC_*L_*4;

  u16*   Xbf   = (u16*)(ws + o_Xbf);
  u16*   Xlin  = (u16*)(ws + o_Xlin);
  u16*   WyT   = (u16*)(ws + o_WyT);
  u16*   WxT   = (u16*)(ws + o_WxT);
  u16*   WoT   = (u16*)(ws + o_WoT);
  u16*   Gt    = (u16*)(ws + o_Gt);
  float* gbias = (float*)(ws + o_gb);
  float* c8    = (float*)(ws + o_c8);
  u16*   Y     = (u16*)(ws + o_Y);
  u16*   xconv = (u16*)(ws + o_xc);
  u16*   Gp    = (u16*)(ws + o_Xbf);   // reuse: Xbf+Xlin dead after fused GEMM+conv
  u16*   Z     = (u16*)(ws + o_xc);    // reuse: xconv dead after gates_pw
  u16*   Ae    = (u16*)(ws + o_Ae);
  u16*   Nr    = (u16*)(ws + o_Nr);
  float* Ach   = (float*)(ws + o_Ach);
  float* Hch   = (float*)(ws + o_Hch);
  float* Hcar  = (float*)(ws + o_Hca);

  dim3 blk(256);
  // prep
  transpose_cvt<<<dim3(32,32), blk, 0, stream>>>(Wy,  WyT, 2048, 2048);
  transpose_cvt<<<dim3(32,32), blk, 0, stream>>>(Wx,  WxT, 2048, 2048);
  transpose_cvt<<<dim3(32,32), blk, 0, stream>>>(Wout,WoT, 2048, 2048);
  prep_small<<<dim3(2048), blk, 0, stream>>>(igw, rgw, igb, rgb, rec, Gt, gbias, c8);
  cvt_x<<<dim3(8192), blk, 0, stream>>>(X, Xbf);
  // fused y+x linears: Bt = [WyT ; WxT] (contiguous), N=4096; cols<2048 -> Y (gelu),
  // cols>=2048 -> Xlin (no gelu)
  gemm_bf16<<<dim3(32,64), blk, 0, stream>>>(Xbf, H_, WyT, H_, by, bx, Y, Xlin, L_, 0, 1, 0);
  // conv
  conv_k<<<dim3(8192), blk, 0, stream>>>(Xlin, cw, cb, xconv);
  // block-diagonal gate GEMM (writes Gp over dead Xbf/Xlin region)
  gemm_bf16<<<dim3(32,64), blk, 0, stream>>>(xconv, L_, Gt, 128, gbias, gbias, Gp, nullptr, NH_*256, 1, 0, 0);
  // pointwise gates
  gates_pw<<<dim3(8192), blk, 0, stream>>>(Gp, xconv, c8, pos, Ae, Nr);
  // chunked scan
  scan1<<<dim3(1024), blk, 0, stream>>>(Ae, Nr, Ach, Hch);
  scan2<<<dim3(16),   blk, 0, stream>>>(Ach, Hch, Hcar);
  scan3<<<dim3(1024), blk, 0, stream>>>(Ae, Nr, Hcar, Y, Z);
  // output projection into d_out (fp32)
  gemm_bf16<<<dim3(16,64), blk, 0, stream>>>(Z, L_, WoT, L_, bout, bout, out, nullptr, H_, 0, 0, 1);
}